// Round 3
// baseline (6334.904 us; speedup 1.0000x reference)
//
#include <hip/hip_runtime.h>
#include <hip/hip_bf16.h>
#include <stdint.h>

typedef unsigned short u16;
typedef __bf16 bf16t;
typedef __attribute__((ext_vector_type(8))) bf16t bf16x8;
typedef __attribute__((ext_vector_type(4))) float f32x4;

#define B_   512
#define N_   100
#define P_   20
#define E_   256
#define H_   512
#define G4H_ 2048
#define BT_  (B_ * N_)   // 51200
#define BC_  128         // phase-B batch chunk
#define NCHUNK_ (B_ / BC_)

__device__ __forceinline__ float bfu2f(unsigned u) {
    union { unsigned i; float f; } v; v.i = u << 16; return v.f;
}
__device__ __forceinline__ float bf2f(u16 x) { return bfu2f((unsigned)x); }
__device__ __forceinline__ u16 f2bf(float f) {
    union { float f; unsigned i; } v; v.f = f;
    unsigned r = v.i + 0x7FFFu + ((v.i >> 16) & 1u);
    return (u16)(r >> 16);
}
__device__ __forceinline__ void unpack8(uint4 r, float* o) {
    o[0] = bfu2f(r.x & 0xffffu); o[1] = bfu2f(r.x >> 16);
    o[2] = bfu2f(r.y & 0xffffu); o[3] = bfu2f(r.y >> 16);
    o[4] = bfu2f(r.z & 0xffffu); o[5] = bfu2f(r.z >> 16);
    o[6] = bfu2f(r.w & 0xffffu); o[7] = bfu2f(r.w >> 16);
}
__device__ __forceinline__ float tanh_f(float x) {
    x = fminf(15.f, fmaxf(-15.f, x));
    float e = __expf(2.f * x);
    return __fdividef(e - 1.f, e + 1.f);
}
__device__ __forceinline__ float sig_f(float x) {
    x = fminf(15.f, fmaxf(-15.f, x));
    return __fdividef(1.f, 1.f + __expf(-x));
}
__device__ __forceinline__ f32x4 mfma16(bf16x8 a, bf16x8 b, f32x4 c) {
    return __builtin_amdgcn_mfma_f32_16x16x32_bf16(a, b, c, 0, 0, 0);
}

// ---------------------------------------------------------------------------
__global__ void sentinel_kernel(float* out) {
    int i = blockIdx.x * 256 + threadIdx.x;
    if (i < B_) out[BT_ + i] = 1.0e9f;   // signals "workspace too small"
}

// init: zero c, zero_h, ll; broadcast dec_input0 rows
__global__ void init_kernel(float* c, u16* zero_h, float* ll, u16* dec0_rows,
                            const u16* __restrict__ dec0) {
    int i = blockIdx.x * 256 + threadIdx.x;          // 262144 threads
    if (i < B_ * H_) { c[i] = 0.f; zero_h[i] = 0; }
    if (i < B_) ll[i] = 0.f;
    if (i < B_ * E_) dec0_rows[i] = dec0[i & (E_ - 1)];
}

// embed[b,n,e] = sum_p x[b,n,p] * emb_W[e,p]
__global__ void embed_kernel(const u16* __restrict__ x, const u16* __restrict__ emb_W,
                             u16* __restrict__ embed) {
    __shared__ float xs[P_];
    int bt = blockIdx.x, tid = threadIdx.x;
    if (tid < P_) xs[tid] = bf2f(x[(size_t)bt * P_ + tid]);
    __syncthreads();
    float s = 0.f;
#pragma unroll
    for (int p = 0; p < P_; ++p) s += xs[p] * bf2f(emb_W[tid * P_ + p]);
    embed[(size_t)bt * E_ + tid] = f2bf(s);
}

// mask[b,t,n] = #{s<t : y[b,s]==n}   (cumulative COUNT, y may repeat)
__global__ void mask_kernel(const int* __restrict__ y, unsigned char* __restrict__ mask) {
    int b = blockIdx.x, n = threadIdx.x;
    if (n >= N_) return;
    unsigned char cnt = 0;
    for (int t = 0; t < N_; ++t) {
        mask[((size_t)b * N_ + t) * N_ + n] = cnt;
        if (y[b * N_ + t] == n) cnt++;
    }
}

// ---------------------------------------------------------------------------
// Generic bf16 GEMM: C[M,N] = A[M,K] @ Bw[N,K]^T + bias, 64x64 tile, BK=32
__global__ __launch_bounds__(256) void gemm_bt_kernel(
    const u16* __restrict__ A, int lda,
    const u16* __restrict__ Bw,
    const u16* __restrict__ bias,
    u16* __restrict__ C, int ldc, int K)
{
    __shared__ __align__(16) short As[64 * 40];
    __shared__ __align__(16) short Bs[64 * 40];
    const int tid = threadIdx.x;
    const int bn = blockIdx.x, bm = blockIdx.y;
    const int srow = tid >> 2, koff = (tid & 3) * 8;
    const size_t aBase = (size_t)(bm * 64 + srow) * lda + koff;
    const size_t bBase = (size_t)(bn * 64 + srow) * K + koff;
    const int NKT = K >> 5;
    uint4 aReg = *(const uint4*)(A + aBase);
    uint4 bReg = *(const uint4*)(Bw + bBase);
    const int w = tid >> 6, l = tid & 63;
    const int wm = w & 1, wn = w >> 1;
    const int rl = l & 15, q8 = (l >> 4) * 8;
    f32x4 acc00 = {0.f,0.f,0.f,0.f}, acc01 = {0.f,0.f,0.f,0.f};
    f32x4 acc10 = {0.f,0.f,0.f,0.f}, acc11 = {0.f,0.f,0.f,0.f};
    short* asw = &As[srow * 40 + koff];
    short* bsw = &Bs[srow * 40 + koff];
    const short* ar0 = &As[(wm * 32 + rl) * 40 + q8];
    const short* ar1 = &As[(wm * 32 + 16 + rl) * 40 + q8];
    const short* br0 = &Bs[(wn * 32 + rl) * 40 + q8];
    const short* br1 = &Bs[(wn * 32 + 16 + rl) * 40 + q8];
    for (int kt = 0; kt < NKT; ++kt) {
        __syncthreads();
        *(uint4*)asw = aReg;
        *(uint4*)bsw = bReg;
        __syncthreads();
        if (kt + 1 < NKT) {
            aReg = *(const uint4*)(A + aBase + (kt + 1) * 32);
            bReg = *(const uint4*)(Bw + bBase + (kt + 1) * 32);
        }
        bf16x8 a0 = *(const bf16x8*)ar0;
        bf16x8 a1 = *(const bf16x8*)ar1;
        bf16x8 b0 = *(const bf16x8*)br0;
        bf16x8 b1 = *(const bf16x8*)br1;
        acc00 = mfma16(a0, b0, acc00);
        acc01 = mfma16(a0, b1, acc01);
        acc10 = mfma16(a1, b0, acc10);
        acc11 = mfma16(a1, b1, acc11);
    }
    const int col0 = bn * 64 + wn * 32 + rl;
    const int row0 = bm * 64 + wm * 32 + (l >> 4) * 4;
    const float bv0 = bias ? bf2f(bias[col0]) : 0.f;
    const float bv1 = bias ? bf2f(bias[col0 + 16]) : 0.f;
#pragma unroll
    for (int r = 0; r < 4; ++r) {
        C[(size_t)(row0 + r) * ldc + col0]           = f2bf(acc00[r] + bv0);
        C[(size_t)(row0 + r) * ldc + col0 + 16]      = f2bf(acc01[r] + bv1);
        C[(size_t)(row0 + 16 + r) * ldc + col0]      = f2bf(acc10[r] + bv0);
        C[(size_t)(row0 + 16 + r) * ldc + col0 + 16] = f2bf(acc11[r] + bv1);
    }
}

// ---------------------------------------------------------------------------
// Per-step fused gates GEMM: gates[b,g] = [h | x_t] @ [Whh | Wih]^T
// M=512, N=2048, K=768 (512 h + 256 x).  mode 0: enc (x=embed[b,t])
// mode 1: dec t=0 (x=dec0_rows[b])   mode 2: dec (x=embed[b, y[b,t-1]])
__global__ __launch_bounds__(256) void step_gemm_kernel(
    const u16* __restrict__ h_base, int h_lda,
    const u16* __restrict__ x_base,
    const int* __restrict__ y,
    const u16* __restrict__ Whh,
    const u16* __restrict__ Wih,
    float* __restrict__ gates,
    int mode, int t)
{
    __shared__ __align__(16) short As[64 * 40];
    __shared__ __align__(16) short Bs[64 * 40];
    const int tid = threadIdx.x;
    const int bn = blockIdx.x, bm = blockIdx.y;
    const int srow = tid >> 2, koff = (tid & 3) * 8;
    const int brw = bm * 64 + srow;     // batch row
    const int grw = bn * 64 + srow;     // gate row
    size_t xrow;
    if (mode == 0)      xrow = ((size_t)brw * N_ + t) * E_;
    else if (mode == 1) xrow = (size_t)brw * E_;
    else                xrow = ((size_t)brw * N_ + (size_t)y[brw * N_ + t - 1]) * E_;
    const u16* hp  = h_base + (size_t)brw * h_lda + koff;
    const u16* xp  = x_base + xrow + koff;
    const u16* whp = Whh + (size_t)grw * H_ + koff;
    const u16* wip = Wih + (size_t)grw * E_ + koff;
    const int w = tid >> 6, l = tid & 63;
    const int wm = w & 1, wn = w >> 1;
    const int rl = l & 15, q8 = (l >> 4) * 8;
    f32x4 acc00 = {0.f,0.f,0.f,0.f}, acc01 = {0.f,0.f,0.f,0.f};
    f32x4 acc10 = {0.f,0.f,0.f,0.f}, acc11 = {0.f,0.f,0.f,0.f};
    short* asw = &As[srow * 40 + koff];
    short* bsw = &Bs[srow * 40 + koff];
    const short* ar0 = &As[(wm * 32 + rl) * 40 + q8];
    const short* ar1 = &As[(wm * 32 + 16 + rl) * 40 + q8];
    const short* br0 = &Bs[(wn * 32 + rl) * 40 + q8];
    const short* br1 = &Bs[(wn * 32 + 16 + rl) * 40 + q8];
    uint4 aReg = *(const uint4*)hp;
    uint4 bReg = *(const uint4*)whp;
    for (int kt = 0; kt < 24; ++kt) {
        __syncthreads();
        *(uint4*)asw = aReg;
        *(uint4*)bsw = bReg;
        __syncthreads();
        const int kn = kt + 1;
        if (kn < 24) {
            if (kn < 16) {
                aReg = *(const uint4*)(hp + kn * 32);
                bReg = *(const uint4*)(whp + kn * 32);
            } else {
                aReg = *(const uint4*)(xp + (kn - 16) * 32);
                bReg = *(const uint4*)(wip + (kn - 16) * 32);
            }
        }
        bf16x8 a0 = *(const bf16x8*)ar0;
        bf16x8 a1 = *(const bf16x8*)ar1;
        bf16x8 b0 = *(const bf16x8*)br0;
        bf16x8 b1 = *(const bf16x8*)br1;
        acc00 = mfma16(a0, b0, acc00);
        acc01 = mfma16(a0, b1, acc01);
        acc10 = mfma16(a1, b0, acc10);
        acc11 = mfma16(a1, b1, acc11);
    }
    const int col0 = bn * 64 + wn * 32 + rl;
    const int row0 = bm * 64 + wm * 32 + (l >> 4) * 4;
#pragma unroll
    for (int r = 0; r < 4; ++r) {
        gates[(size_t)(row0 + r) * G4H_ + col0]           = acc00[r];
        gates[(size_t)(row0 + r) * G4H_ + col0 + 16]      = acc01[r];
        gates[(size_t)(row0 + 16 + r) * G4H_ + col0]      = acc10[r];
        gates[(size_t)(row0 + 16 + r) * G4H_ + col0 + 16] = acc11[r];
    }
}

// LSTM pointwise: PyTorch gate order i,f,g,o
__global__ void lstm_pw_kernel(const float* __restrict__ gates,
                               const u16* __restrict__ bih, const u16* __restrict__ bhh,
                               float* __restrict__ c,
                               u16* __restrict__ h_out, int h_ldc)
{
    int idx = blockIdx.x * 256 + threadIdx.x;   // B_*H_ threads
    int b = idx >> 9, hh = idx & (H_ - 1);
    const size_t gb = (size_t)b * G4H_;
    float gi = gates[gb + hh]             + bf2f(bih[hh])             + bf2f(bhh[hh]);
    float gf = gates[gb + H_ + hh]        + bf2f(bih[H_ + hh])        + bf2f(bhh[H_ + hh]);
    float gg = gates[gb + 2 * H_ + hh]    + bf2f(bih[2 * H_ + hh])    + bf2f(bhh[2 * H_ + hh]);
    float go = gates[gb + 3 * H_ + hh]    + bf2f(bih[3 * H_ + hh])    + bf2f(bhh[3 * H_ + hh]);
    float cv = sig_f(gf) * c[idx] + sig_f(gi) * tanh_f(gg);
    c[idx] = cv;
    h_out[(size_t)b * h_ldc + hh] = f2bf(sig_f(go) * tanh_f(cv));
}

// ---------------------------------------------------------------------------
// Glimpse over one batch chunk: all pointers pre-offset to the chunk base.
// u[n]=Vec.tanh(q1+u2g[n]); a=softmax(u-1e8*mask); query2 = a @ ref
__global__ __launch_bounds__(256) void glimpse_kernel(
    const u16* __restrict__ q1, const u16* __restrict__ u2g,
    const u16* __restrict__ ref, const u16* __restrict__ Vec,
    const unsigned char* __restrict__ mask, u16* __restrict__ query2)
{
    const int bt = blockIdx.x, b = bt / N_;
    const int tid = threadIdx.x, w = tid >> 6, l = tid & 63;
    __shared__ float u_s[N_], a_s[N_], red[8];
    const int h0 = l * 8;
    float qv[8], vv[8];
    uint4 qa = *(const uint4*)(q1 + (size_t)bt * H_ + h0);
    uint4 va = *(const uint4*)(Vec + h0);
    unpack8(qa, qv); unpack8(va, vv);
    const u16* ub = u2g + (size_t)b * N_ * H_;
    for (int n = w * 25; n < w * 25 + 25; ++n) {
        uint4 ua = *(const uint4*)(ub + (size_t)n * H_ + h0);
        float uv[8]; unpack8(ua, uv);
        float s = 0.f;
#pragma unroll
        for (int j = 0; j < 8; ++j) s += vv[j] * tanh_f(qv[j] + uv[j]);
#pragma unroll
        for (int off = 32; off > 0; off >>= 1) s += __shfl_xor(s, off, 64);
        if (l == 0) u_s[n] = s;
    }
    __syncthreads();
    const unsigned char* mrow = mask + (size_t)bt * N_;
    float v = -3.0e38f;
    if (tid < N_) v = u_s[tid] - 1e8f * (float)mrow[tid];
    float m = v;
#pragma unroll
    for (int off = 32; off > 0; off >>= 1) m = fmaxf(m, __shfl_xor(m, off, 64));
    if (l == 0) red[w] = m;
    __syncthreads();
    float mx = fmaxf(fmaxf(red[0], red[1]), fmaxf(red[2], red[3]));
    float e = (tid < N_) ? __expf(v - mx) : 0.f;
    float s2 = e;
#pragma unroll
    for (int off = 32; off > 0; off >>= 1) s2 += __shfl_xor(s2, off, 64);
    if (l == 0) red[4 + w] = s2;
    __syncthreads();
    float inv = __fdividef(1.f, red[4] + red[5] + red[6] + red[7]);
    if (tid < N_) a_s[tid] = e * inv;
    __syncthreads();
    const u16* refb = ref + (size_t)b * N_ * H_;
    float acc0 = 0.f, acc1 = 0.f;
    const int hh = tid * 2;
    for (int n = 0; n < N_; ++n) {
        float a = a_s[n];
        unsigned rr = *(const unsigned*)(refb + (size_t)n * H_ + hh);
        acc0 += a * bfu2f(rr & 0xffffu);
        acc1 += a * bfu2f(rr >> 16);
    }
    unsigned packed = ((unsigned)f2bf(acc1) << 16) | (unsigned)f2bf(acc0);
    *(unsigned*)(query2 + (size_t)bt * H_ + hh) = packed;
}

// Pointer head over one batch chunk (pointers pre-offset):
// u[n]=Vec2.tanh(q2+u2p[n]); u=10*tanh(u); logits=u-1e8*mask;
// log_softmax -> ps (float32!); atomicAdd picked log-prob into ll
__global__ __launch_bounds__(256) void final_attn_kernel(
    const u16* __restrict__ q2, const u16* __restrict__ u2p,
    const u16* __restrict__ Vec2, const unsigned char* __restrict__ mask,
    const int* __restrict__ y, float* __restrict__ ll, float* __restrict__ ps)
{
    const int bt = blockIdx.x, b = bt / N_;
    const int tid = threadIdx.x, w = tid >> 6, l = tid & 63;
    __shared__ float u_s[N_], lp_s[N_], red[8];
    const int h0 = l * 8;
    float qv[8], vv[8];
    uint4 qa = *(const uint4*)(q2 + (size_t)bt * H_ + h0);
    uint4 va = *(const uint4*)(Vec2 + h0);
    unpack8(qa, qv); unpack8(va, vv);
    const u16* ub = u2p + (size_t)b * N_ * H_;
    for (int n = w * 25; n < w * 25 + 25; ++n) {
        uint4 ua = *(const uint4*)(ub + (size_t)n * H_ + h0);
        float uv[8]; unpack8(ua, uv);
        float s = 0.f;
#pragma unroll
        for (int j = 0; j < 8; ++j) s += vv[j] * tanh_f(qv[j] + uv[j]);
#pragma unroll
        for (int off = 32; off > 0; off >>= 1) s += __shfl_xor(s, off, 64);
        if (l == 0) u_s[n] = s;
    }
    __syncthreads();
    const unsigned char* mrow = mask + (size_t)bt * N_;
    float lg = -3.0e38f;
    if (tid < N_) lg = 10.f * tanh_f(u_s[tid]) - 1e8f * (float)mrow[tid];
    float m = lg;
#pragma unroll
    for (int off = 32; off > 0; off >>= 1) m = fmaxf(m, __shfl_xor(m, off, 64));
    if (l == 0) red[w] = m;
    __syncthreads();
    float mx = fmaxf(fmaxf(red[0], red[1]), fmaxf(red[2], red[3]));
    float e = (tid < N_) ? __expf(lg - mx) : 0.f;
    float s2 = e;
#pragma unroll
    for (int off = 32; off > 0; off >>= 1) s2 += __shfl_xor(s2, off, 64);
    if (l == 0) red[4 + w] = s2;
    __syncthreads();
    float lse = mx + __logf(red[4] + red[5] + red[6] + red[7]);
    if (tid < N_) {
        float lp = lg - lse;
        ps[(size_t)bt * N_ + tid] = lp;       // float32 output
        lp_s[tid] = lp;
    }
    __syncthreads();
    if (tid == 0) atomicAdd(&ll[b], lp_s[y[bt]]);
}

// outputs (float32): pi = float(y); ll from f32 accumulator
__global__ void write_out_kernel(const int* __restrict__ y, const float* __restrict__ ll,
                                 float* __restrict__ out) {
    int i = blockIdx.x * 256 + threadIdx.x;   // 51200 threads
    if (i < BT_) out[i] = (float)y[i];
    if (i < B_)  out[BT_ + i] = ll[i];
}

// ---------------------------------------------------------------------------
extern "C" void kernel_launch(void* const* d_in, const int* in_sizes, int n_in,
                              void* d_out, int out_size, void* d_ws, size_t ws_size,
                              hipStream_t stream)
{
    const u16* x        = (const u16*)d_in[0];
    const int* y        = (const int*)d_in[1];
    const u16* emb_W    = (const u16*)d_in[2];
    const u16* enc_Wih  = (const u16*)d_in[3];
    const u16* enc_Whh  = (const u16*)d_in[4];
    const u16* enc_bih  = (const u16*)d_in[5];
    const u16* enc_bhh  = (const u16*)d_in[6];
    const u16* dec_Wih  = (const u16*)d_in[7];
    const u16* dec_Whh  = (const u16*)d_in[8];
    const u16* dec_bih  = (const u16*)d_in[9];
    const u16* dec_bhh  = (const u16*)d_in[10];
    const u16* Vec      = (const u16*)d_in[11];
    const u16* Vec2     = (const u16*)d_in[12];
    const u16* Wq_W     = (const u16*)d_in[13];
    const u16* Wq_b     = (const u16*)d_in[14];
    const u16* Wref_W   = (const u16*)d_in[15];
    const u16* Wref_b   = (const u16*)d_in[16];
    const u16* Wq2_W    = (const u16*)d_in[17];
    const u16* Wq2_b    = (const u16*)d_in[18];
    const u16* Wref2_W  = (const u16*)d_in[19];
    const u16* Wref2_b  = (const u16*)d_in[20];
    const u16* dec0     = (const u16*)d_in[21];

    // workspace carve (all 256-B aligned).
    // Dead-zone buffers (embed/gates/cbuf/zero_h/dec0_rows) die when the
    // decoder finishes; phase-B chunk buffers Y,Z (13.1 MB each) alias them.
    char* p = (char*)d_ws;
    auto carve = [&](size_t bytes) -> char* {
        char* r = p; p += (bytes + 255) & ~(size_t)255; return r;
    };
    char*  deadzone  = p;
    u16*   embed     = (u16*)  carve((size_t)BT_ * E_ * 2);      // 26.21 MB
    float* gates     = (float*)carve((size_t)B_ * G4H_ * 4);     //  4.19 MB
    float* cbuf      = (float*)carve((size_t)B_ * H_ * 4);       //  1.05 MB
    u16*   zero_h    = (u16*)  carve((size_t)B_ * H_ * 2);       //  0.52 MB
    u16*   dec0_rows = (u16*)  carve((size_t)B_ * E_ * 2);       //  0.26 MB
    u16*   ref       = (u16*)  carve((size_t)BT_ * H_ * 2);      // 52.43 MB
    u16*   dec_hs    = (u16*)  carve((size_t)BT_ * H_ * 2);      // 52.43 MB (later: qry2)
    unsigned char* maskb = (unsigned char*)carve((size_t)BT_ * N_); // 5.12 MB
    float* llb       = (float*)carve((size_t)B_ * 4);
    const size_t need = (size_t)(p - (char*)d_ws);
    // phase-B chunk buffers alias the dead zone (2 x 13.11 MB <= 32.24 MB)
    u16* Ybuf = (u16*)deadzone;                                   // u2g / u2p chunk
    u16* Zbuf = (u16*)(deadzone + (size_t)BC_ * N_ * H_ * 2);     // q1 / q2 chunk

    if (need > ws_size) {   // workspace too small: write detectable sentinel
        sentinel_kernel<<<(B_ + 255) / 256, 256, 0, stream>>>((float*)d_out);
        return;
    }

    init_kernel<<<(B_ * H_) / 256, 256, 0, stream>>>(cbuf, zero_h, llb, dec0_rows, dec0);
    embed_kernel<<<BT_, 256, 0, stream>>>(x, emb_W, embed);
    mask_kernel<<<B_, 128, 0, stream>>>(y, maskb);

    dim3 sgrid(G4H_ / 64, B_ / 64);   // (32, 8)
    // ---- encoder recurrence ----
    for (int t = 0; t < N_; ++t) {
        const u16* hb = (t == 0) ? zero_h : (ref + (size_t)(t - 1) * H_);
        int hlda = (t == 0) ? H_ : (N_ * H_);
        step_gemm_kernel<<<sgrid, 256, 0, stream>>>(hb, hlda, embed, y,
                                                    enc_Whh, enc_Wih, gates, 0, t);
        lstm_pw_kernel<<<(B_ * H_) / 256, 256, 0, stream>>>(gates, enc_bih, enc_bhh,
                                                            cbuf, ref + (size_t)t * H_, N_ * H_);
    }
    // ---- decoder recurrence (inputs known: dec0 then embed[b, y[b,t-1]]) ----
    for (int t = 0; t < N_; ++t) {
        const u16* hb = (t == 0) ? (ref + (size_t)(N_ - 1) * H_) : (dec_hs + (size_t)(t - 1) * H_);
        const u16* xb = (t == 0) ? dec0_rows : embed;
        int mode = (t == 0) ? 1 : 2;
        step_gemm_kernel<<<sgrid, 256, 0, stream>>>(hb, N_ * H_, xb, y,
                                                    dec_Whh, dec_Wih, gates, mode, t);
        lstm_pw_kernel<<<(B_ * H_) / 256, 256, 0, stream>>>(gates, dec_bih, dec_bhh,
                                                            cbuf, dec_hs + (size_t)t * H_, N_ * H_);
    }
    // ---- batched attention, chunked over batch (embed/gates now dead) ----
    float* out = (float*)d_out;
    const int MC = BC_ * N_;                     // 12800 rows per chunk
    dim3 cgrid(H_ / 64, MC / 64);                // (8, 200)
    for (int c = 0; c < NCHUNK_; ++c) {
        const size_t rowOff = (size_t)c * BC_ * N_ * H_;   // chunk offset in [B*N,H]
        const size_t btOff  = (size_t)c * BC_ * N_;
        // q1 = dec_hs[chunk] @ Wq^T + b       -> Z
        gemm_bt_kernel<<<cgrid, 256, 0, stream>>>(dec_hs + rowOff, H_, Wq_W,  Wq_b,  Zbuf, H_, H_);
        // u2g = ref[chunk] @ Wref^T + b       -> Y
        gemm_bt_kernel<<<cgrid, 256, 0, stream>>>(ref + rowOff,    H_, Wref_W, Wref_b, Ybuf, H_, H_);
        // glimpse -> qry2 overwrites dec_hs[chunk]
        glimpse_kernel<<<MC, 256, 0, stream>>>(Zbuf, Ybuf, ref + rowOff, Vec,
                                               maskb + btOff * N_, dec_hs + rowOff);
        // q2 = qry2[chunk] @ Wq2^T + b        -> Z
        gemm_bt_kernel<<<cgrid, 256, 0, stream>>>(dec_hs + rowOff, H_, Wq2_W, Wq2_b, Zbuf, H_, H_);
        // u2p = ref[chunk] @ Wref2^T + b      -> Y
        gemm_bt_kernel<<<cgrid, 256, 0, stream>>>(ref + rowOff,    H_, Wref2_W, Wref2_b, Ybuf, H_, H_);
        // pointer head -> ps (float32) + ll
        final_attn_kernel<<<MC, 256, 0, stream>>>(Zbuf, Ybuf, Vec2, maskb + btOff * N_,
                                                  y + btOff, llb + (size_t)c * BC_,
                                                  out + BT_ + B_ + btOff * N_);
    }
    write_out_kernel<<<BT_ / 256, 256, 0, stream>>>(y, llb, out);
}